// Round 7
// baseline (725.411 us; speedup 1.0000x reference)
//
#include <hip/hip_runtime.h>

typedef unsigned short u16;
typedef __bf16 bf16x8 __attribute__((ext_vector_type(8)));
typedef float f32x4 __attribute__((ext_vector_type(4)));

__device__ __forceinline__ float bf2f(u16 u) {
  union { unsigned int i; float f; } v; v.i = ((unsigned int)u) << 16; return v.f;
}
__device__ __forceinline__ u16 f2bf(float f) {
  union { float f; unsigned int i; } v; v.f = f;
  unsigned int i = v.i;
  return (u16)((i + 0x7fffu + ((i >> 16) & 1u)) >> 16);  // RNE
}
__device__ __forceinline__ float ldf(const float* p) { return *p; }
__device__ __forceinline__ float ldf(const u16* p) { return bf2f(*p); }

// async global->LDS, 16B per lane. LDS dest must be the wave-uniform base;
// HW writes base + lane*16 (guide §5: m97/m104).
__device__ __forceinline__ void load_lds16(const u16* g, u16* l) {
  __builtin_amdgcn_global_load_lds(
      (const __attribute__((address_space(1))) unsigned int*)g,
      (__attribute__((address_space(3))) unsigned int*)l, 16, 0, 0);
}

// ---------------- weight transpose + cast: Wt[n*K+k] = bf16(W[k*N+n]) ----
__global__ void transpose_kernel(const float* __restrict__ W, u16* __restrict__ Wt,
                                 int K, int N) {
  int idx = blockIdx.x * 256 + threadIdx.x;
  if (idx >= K * N) return;
  int k = idx / N, n = idx % N;
  Wt[n * K + k] = f2bf(W[idx]);
}

// ---------------- layernorm over C=576, 4 rows/block (1 wave each) -------
template <typename T>
__global__ __launch_bounds__(256) void ln_kernel(const T* __restrict__ x,
                                                 const float* __restrict__ w,
                                                 const float* __restrict__ b,
                                                 u16* __restrict__ out) {
  int wave = threadIdx.x >> 6, lane = threadIdx.x & 63;
  long row = (long)blockIdx.x * 4 + wave;
  const T* xr = x + row * 576;
  float v[9];
  float sum = 0.f;
  #pragma unroll
  for (int i = 0; i < 9; ++i) { v[i] = ldf(&xr[lane + i * 64]); sum += v[i]; }
  #pragma unroll
  for (int off = 32; off; off >>= 1) sum += __shfl_xor(sum, off);
  float mean = sum * (1.0f / 576.0f);
  float var = 0.f;
  #pragma unroll
  for (int i = 0; i < 9; ++i) { float d = v[i] - mean; var += d * d; }
  #pragma unroll
  for (int off = 32; off; off >>= 1) var += __shfl_xor(var, off);
  float rstd = rsqrtf(var * (1.0f / 576.0f) + 1e-5f);
  u16* outr = out + row * 576;
  #pragma unroll
  for (int i = 0; i < 9; ++i) {
    int c = lane + i * 64;
    outr[c] = f2bf((v[i] - mean) * rstd * w[c] + b[c]);
  }
}

// ---------------- DMlp gather: pixelshuffle(3) + reflpad(2) + masked unfold
// chunk-local: ln2 points at chunk start (whole batches), b chunk-relative.
__constant__ int c_di[25] = {0,0,0, 1,1,1, 2,2,2, 3,3,3,3,3,3,3, 4,4,4, 5,5,5, 6,6,6};
__constant__ int c_dj[25] = {0,3,6, 1,3,5, 2,3,4, 0,1,2,3,4,5,6, 2,3,4, 1,3,5, 0,3,6};

__device__ __forceinline__ int refl168(int t) {
  return t < 0 ? -t : (t >= 168 ? 334 - t : t);
}

__global__ __launch_bounds__(256) void gather_kernel(const u16* __restrict__ ln2,
                                                     u16* __restrict__ cols) {
  int idx = blockIdx.x * 256 + threadIdx.x;
  int f = idx % 1600;
  int n_ = idx / 1600;            // b*3136 + i*56 + j  (b chunk-relative)
  int bj = n_ % 3136, b = n_ / 3136;
  int i = bj / 56, j = bj % 56;
  int p = f % 25, nf = f / 25;
  int R  = refl168(c_di[p] + 3 * i - 2);
  int Cc = refl168(c_dj[p] + 3 * j - 2);
  int h2 = R / 3, a = R - 3 * h2;
  int w2 = Cc / 3, b2 = Cc - 3 * w2;
  long src = ((long)b * 3136 + h2 * 56 + w2) * 576 + nf * 9 + a * 3 + b2;
  cols[idx] = ln2[src];
}

// ---------------- window attention, MFMA version -------------------------
// one block per (window, head); 4 waves. QK^T and PV via mfma_f32_16x16x32_bf16
__global__ __launch_bounds__(256) void attn_kernel(const u16* __restrict__ qkv,
                                                   const float* __restrict__ rpb,
                                                   u16* __restrict__ obuf) {
  int h = blockIdx.y;            // 0..5
  int wi = blockIdx.x;
  int b = wi >> 6, w = wi & 63, wr = w >> 3, wc = w & 7;
  __shared__ __align__(16) u16 Qs[64 * 104];   // [t][d] stride 104 (16B-aligned rows)
  __shared__ __align__(16) u16 Ks[64 * 104];
  __shared__ __align__(16) u16 Vt[96 * 72];    // [d][t] transposed, cols 49..63 zeroed
  __shared__ __align__(16) u16 Ps[64 * 72];    // P bf16, [i][j], pad cols exactly 0
  int tid = threadIdx.x;
  int lane = tid & 63, wv = tid >> 6;
  int quad = lane >> 4, l15 = lane & 15;
  const float scale = 0.1020620726159658f;  // 96^-0.5

  long base = ((long)b * 3136 + wr * 7 * 56 + wc * 7) * 1728 + h * 96;

  // stage Q,K: coalesced uint4 (dq fastest), conflict-free b128 writes
  for (int idx = tid; idx < 588; idx += 256) {
    int t = idx / 12, dq = idx % 12;
    int tr = t / 7, tc = t - tr * 7;
    long roff = base + (tr * 56 + tc) * 1728 + dq * 8;
    *(uint4*)&Qs[t * 104 + dq * 8] = *(const uint4*)(qkv + roff);
    *(uint4*)&Ks[t * 104 + dq * 8] = *(const uint4*)(qkv + roff + 576);
  }
  // Vt pad cols (j = 49..63) must be 0: they multiply Ps pad cols (0) in MFMA
  for (int idx = tid; idx < 96 * 15; idx += 256) {
    int d = idx / 15, t = 49 + idx % 15;
    Vt[d * 72 + t] = 0;
  }
  // stage V transposed: t-fastest lane mapping -> conflict-free u16 LDS writes
  for (int idx = tid; idx < 768; idx += 256) {
    int dq = idx >> 6, t = idx & 63;
    if (t < 49) {
      int tr = t / 7, tc = t - tr * 7;
      uint4 v = *(const uint4*)(qkv + base + (tr * 56 + tc) * 1728 + 1152 + dq * 8);
      const u16* vv = (const u16*)&v;
      #pragma unroll
      for (int kk = 0; kk < 8; ++kk) Vt[(dq * 8 + kk) * 72 + t] = vv[kk];
    }
  }
  __syncthreads();

  // ---- QK^T: wave wv owns S rows [wv*16, wv*16+16) ----
  f32x4 accS[4] = {};
  #pragma unroll
  for (int k0 = 0; k0 < 3; ++k0) {
    bf16x8 aq = *(const bf16x8*)&Qs[(wv * 16 + l15) * 104 + k0 * 32 + quad * 8];
    #pragma unroll
    for (int nt = 0; nt < 4; ++nt) {
      bf16x8 bk = *(const bf16x8*)&Ks[(nt * 16 + l15) * 104 + k0 * 32 + quad * 8];
      accS[nt] = __builtin_amdgcn_mfma_f32_16x16x32_bf16(aq, bk, accS[nt], 0, 0, 0);
    }
  }

  // ---- softmax fully in-register: row r lives in the 16 lanes of one quad ----
  #pragma unroll
  for (int r = 0; r < 4; ++r) {
    int rg = wv * 16 + quad * 4 + r;          // global window-row (0..63)
    int yi = rg / 7, xi = rg - yi * 7;
    float sv[4];
    float mx = -3e38f;
    #pragma unroll
    for (int nt = 0; nt < 4; ++nt) {
      int col = nt * 16 + l15;
      float s = accS[nt][r] * scale;
      if (rg < 49 && col < 49) {
        int yj = col / 7, xj = col - yj * 7;
        s += rpb[((yi - yj + 6) * 13 + (xi - xj + 6)) * 6 + h];
      } else {
        s = -3e38f;                            // masks pad cols AND any NaN from pad LDS
      }
      sv[nt] = s;
      mx = fmaxf(mx, s);
    }
    #pragma unroll
    for (int off = 8; off; off >>= 1) mx = fmaxf(mx, __shfl_xor(mx, off));
    float sum = 0.f;
    #pragma unroll
    for (int nt = 0; nt < 4; ++nt) { sv[nt] = __expf(sv[nt] - mx); sum += sv[nt]; }
    #pragma unroll
    for (int off = 8; off; off >>= 1) sum += __shfl_xor(sum, off);
    float inv = 1.0f / sum;
    u16* psr = Ps + rg * 72;
    #pragma unroll
    for (int nt = 0; nt < 4; ++nt) psr[nt * 16 + l15] = f2bf(sv[nt] * inv);
  }
  __syncthreads();

  // ---- PV: O[i][d] = sum_j P[i][j] * Vt[d][j], K-dim = 64 (pad zeroed) ----
  f32x4 accO[6] = {};
  #pragma unroll
  for (int k0 = 0; k0 < 2; ++k0) {
    bf16x8 ap = *(const bf16x8*)&Ps[(wv * 16 + l15) * 72 + k0 * 32 + quad * 8];
    #pragma unroll
    for (int nt = 0; nt < 6; ++nt) {
      bf16x8 bv = *(const bf16x8*)&Vt[(nt * 16 + l15) * 72 + k0 * 32 + quad * 8];
      accO[nt] = __builtin_amdgcn_mfma_f32_16x16x32_bf16(ap, bv, accO[nt], 0, 0, 0);
    }
  }
  #pragma unroll
  for (int r = 0; r < 4; ++r) {
    int rg = wv * 16 + quad * 4 + r;
    if (rg < 49) {
      int tr = rg / 7, tc = rg - tr * 7;
      long ooff = ((long)b * 3136 + (wr * 7 + tr) * 56 + wc * 7 + tc) * 576 + h * 96;
      #pragma unroll
      for (int nt = 0; nt < 6; ++nt) obuf[ooff + nt * 16 + l15] = f2bf(accO[nt][r]);
    }
  }
}

// ---------------- bf16 MFMA GEMM: C(M,N) = A(M,K) @ Bt(N,K)^T + epi ------
// tile 128x128x32, 256 threads (4 waves, 2x2), global_load_lds width-16
// staging, raw s_barrier + counted vmcnt, XCD-chunked bijective swizzle.
// NBUF selects the pipeline PER CALL SITE (both variants HW-verified):
//   NBUF=2: depth-1 double-buffer, 32 KB LDS. Best for L2-overflow A-streams
//           (fc1: per-XCD A-slice 5 MB > 4 MB L2; R4 measured 113 us vs
//            138/143 us for deeper pipes -- depth>1 HURTS this regime).
//   NBUF=3: depth-2 triple-buffer, 48 KB LDS. Best for L2-resident A
//           (qkv/proj/fc2: A-slice 1.8-3.2 MB; R5 measured rest-of-model
//            511 -> 429 us vs depth-1).
// Requires M % 128 == 0 and K % 32 == 0 (true for all call sites).
// N remainder: B staging row clamped to N-1, stores guarded on col < N.
// EPI: 0 = +bias ; 1 = +bias, exact GELU ; 2 = +bias, +res
template <int NBUF, int EPI, typename TR, typename TO>
__global__ __launch_bounds__(256) void gemm_kernel(const u16* __restrict__ A,
                                                   const u16* __restrict__ Bt,
                                                   const float* __restrict__ bias,
                                                   const TR* __restrict__ res,
                                                   TO* __restrict__ C,
                                                   int M, int N, int K) {
  __shared__ __align__(16) u16 As[NBUF][128 * 32];
  __shared__ __align__(16) u16 Bs[NBUF][128 * 32];

  // XCD-chunked bijective swizzle (T1/m204): each XCD owns a contiguous
  // range of the logical (n-fastest) grid -> A-panel L2 reuse within XCD.
  int nwg = gridDim.x * gridDim.y;
  int flat = blockIdx.y * gridDim.x + blockIdx.x;
  int q = nwg >> 3, r = nwg & 7;
  int xcd = flat & 7, loc = flat >> 3;
  int newflat = ((xcd < r) ? xcd * (q + 1) : r * (q + 1) + (xcd - r) * q) + loc;
  int nblk = newflat % gridDim.x, mblk = newflat / gridDim.x;
  int n0 = nblk * 128;
  int m0 = mblk * 128;

  int tid = threadIdx.x;
  int lane = tid & 63, wv = tid >> 6;
  int quad = lane >> 4, l15 = lane & 15;
  int wr2 = wv >> 1, wc2 = wv & 1;            // wave -> 64x64 quadrant
  f32x4 acc[4][4] = {};

  // per-thread staging chunks (16B): chunk = it*256 + tid ; r = chunk>>2 ; kc = chunk&3
  int rA0 = tid >> 2, rA1 = (256 + tid) >> 2;
  int kc0 = (tid & 3) * 8;
  int rB0 = n0 + rA0; if (rB0 > N - 1) rB0 = N - 1;
  int rB1 = n0 + rA1; if (rB1 > N - 1) rB1 = N - 1;
  const u16* gA0 = A + (long)(m0 + rA0) * K + kc0;
  const u16* gA1 = A + (long)(m0 + rA1) * K + kc0;
  const u16* gB0 = Bt + (long)rB0 * K + kc0;
  const u16* gB1 = Bt + (long)rB1 * K + kc0;
  int lo0 = (wv * 64) * 8, lo1 = (256 + wv * 64) * 8;  // wave-uniform LDS bases

  int nt = K >> 5;

  auto stage = [&](int bufi, int kk) {
    load_lds16(gA0 + kk, &As[bufi][lo0]);
    load_lds16(gA1 + kk, &As[bufi][lo1]);
    load_lds16(gB0 + kk, &Bs[bufi][lo0]);
    load_lds16(gB1 + kk, &Bs[bufi][lo1]);
  };
  auto compute = [&](int cur) {
    bf16x8 a[4], bfr[4];
    const u16* as = &As[cur][(wr2 * 64 + l15) * 32 + quad * 8];
    const u16* bs = &Bs[cur][(wc2 * 64 + l15) * 32 + quad * 8];
    #pragma unroll
    for (int mi = 0; mi < 4; ++mi) a[mi] = *(const bf16x8*)(as + mi * 512);
    #pragma unroll
    for (int ni = 0; ni < 4; ++ni) bfr[ni] = *(const bf16x8*)(bs + ni * 512);
    #pragma unroll
    for (int mi = 0; mi < 4; ++mi)
      #pragma unroll
      for (int ni = 0; ni < 4; ++ni)
        acc[mi][ni] = __builtin_amdgcn_mfma_f32_16x16x32_bf16(a[mi], bfr[ni], acc[mi][ni], 0, 0, 0);
  };

  if constexpr (NBUF == 2) {
    // R4 schedule: depth-1, wait vmcnt(4) steady
    stage(0, 0);
    for (int t = 0; t < nt - 1; ++t) {
      int cur = t & 1;
      stage(cur ^ 1, (t + 1) * 32);
      asm volatile("s_waitcnt vmcnt(4)" ::: "memory");
      __builtin_amdgcn_s_barrier();
      compute(cur);
      __builtin_amdgcn_s_barrier();
    }
    asm volatile("s_waitcnt vmcnt(0)" ::: "memory");
    __builtin_amdgcn_s_barrier();
    compute((nt - 1) & 1);
  } else {
    // R5 schedule: depth-2, wait vmcnt(8) steady, drain 4 -> 0
    stage(0, 0);
    stage(1, 32);
    int cur = 0, nx2 = 2;
    for (int t = 0; t < nt; ++t) {
      if (t + 2 < nt) {
        stage(nx2, (t + 2) * 32);
        asm volatile("s_waitcnt vmcnt(8)" ::: "memory");
      } else if (t + 1 < nt) {
        asm volatile("s_waitcnt vmcnt(4)" ::: "memory");
      } else {
        asm volatile("s_waitcnt vmcnt(0)" ::: "memory");
      }
      __builtin_amdgcn_s_barrier();
      compute(cur);
      __builtin_amdgcn_s_barrier();
      cur = cur + 1; if (cur == 3) cur = 0;
      nx2 = nx2 + 1; if (nx2 == 3) nx2 = 0;
    }
  }

  #pragma unroll
  for (int mi = 0; mi < 4; ++mi)
    #pragma unroll
    for (int ni = 0; ni < 4; ++ni) {
      int col = n0 + wc2 * 64 + ni * 16 + l15;
      if (col < N) {
        float bz = bias[col];
        #pragma unroll
        for (int rr = 0; rr < 4; ++rr) {
          int row = m0 + wr2 * 64 + mi * 16 + quad * 4 + rr;
          float v = acc[mi][ni][rr] + bz;
          if (EPI == 1) v = 0.5f * v * (1.0f + erff(v * 0.70710678118654752f));
          if (EPI == 2) v += ldf(&res[(long)row * N + col]);
          long off = (long)row * N + col;
          if (sizeof(TO) == 2) ((u16*)C)[off] = f2bf(v);
          else                 ((float*)C)[off] = v;
        }
      }
    }
}

// ---------------- host launch -------------------------------------------
// Inputs fp32, OUTPUT FP32. ws peak ~90.6 MB.
// x1 (phase-1 output) lives in d_out as f32: proj writes it, phase-2 LN
// reads it, fc2 reads it as residual and overwrites in place (each element
// touched exactly once, read-before-write in the same thread; phase 1 fully
// rewrites d_out before phase 2 reads -> graph-replay idempotent).
extern "C" void kernel_launch(void* const* d_in, const int* in_sizes, int n_in,
                              void* d_out, int out_size, void* d_ws, size_t ws_size,
                              hipStream_t stream) {
  const float* x      = (const float*)d_in[0];
  const float* n1w    = (const float*)d_in[1];
  const float* n1b    = (const float*)d_in[2];
  const float* qkv_w  = (const float*)d_in[3];
  const float* qkv_b  = (const float*)d_in[4];
  const float* rpb    = (const float*)d_in[5];
  const float* proj_w = (const float*)d_in[6];
  const float* proj_b = (const float*)d_in[7];
  const float* n2w    = (const float*)d_in[8];
  const float* n2b    = (const float*)d_in[9];
  const float* fc1_w  = (const float*)d_in[10];
  const float* fc1_b  = (const float*)d_in[11];
  const float* fc2_w  = (const float*)d_in[12];
  const float* fc2_b  = (const float*)d_in[13];

  char* ws = (char*)d_ws;
  u16* wt_qkv  = (u16*)(ws + 0);           // 1728x576
  u16* wt_proj = (u16*)(ws + 1990656);     // 576x576
  u16* wt_fc1  = (u16*)(ws + 2654208);     // 1024x1600
  u16* wt_fc2  = (u16*)(ws + 5931008);     // 576x1024
  char* qkvpool = ws + 7110656;            // 43,352,064 B (ph1 qkvb / ph2 colsb)
  char* lnpool  = ws + 50462720;           // 14,450,688 B (ph1 lnb / ph2 ln2b)
  char* hpool   = ws + 64913408;           // 25,690,112 B (ph2 hb) end 90,603,520
  float* x1 = (float*)d_out;               // 25088x576 f32

  transpose_kernel<<<3888, 256, 0, stream>>>(qkv_w, wt_qkv, 576, 1728);
  transpose_kernel<<<1296, 256, 0, stream>>>(proj_w, wt_proj, 576, 576);
  transpose_kernel<<<6400, 256, 0, stream>>>(fc1_w, wt_fc1, 1600, 1024);
  transpose_kernel<<<2304, 256, 0, stream>>>(fc2_w, wt_fc2, 1024, 576);

  // ---------- phase 1: two halves of 4 batches (12544 rows each) ----------
  for (int h = 0; h < 2; ++h) {
    const long r0 = (long)h * 12544;
    u16* lnb  = (u16*)lnpool;          // ln1 out, then reused as attn out
    u16* qkvb = (u16*)qkvpool;
    ln_kernel<float><<<3136, 256, 0, stream>>>(x + r0 * 576, n1w, n1b, lnb);
    gemm_kernel<3, 0, float, u16><<<dim3(14, 98), 256, 0, stream>>>(
        lnb, wt_qkv, qkv_b, (const float*)nullptr, qkvb, 12544, 1728, 576);
    attn_kernel<<<dim3(256, 6), 256, 0, stream>>>(qkvb, rpb, lnb);
    gemm_kernel<3, 2, float, float><<<dim3(5, 98), 256, 0, stream>>>(
        lnb, wt_proj, proj_b, x + r0 * 576, x1 + r0 * 576, 12544, 576, 576);
  }

  // ---------- phase 2: two halves of 4 batches (12544 rows each) ----------
  for (int q = 0; q < 2; ++q) {
    const long r0 = (long)q * 12544;
    u16* ln2b  = (u16*)lnpool;                    // 14,450,688 B
    u16* colsb = (u16*)qkvpool;                   // 40,140,800 B
    u16* hb    = (u16*)hpool;                     // 25,690,112 B
    ln_kernel<float><<<3136, 256, 0, stream>>>(x1 + r0 * 576, n2w, n2b, ln2b);
    gather_kernel<<<78400, 256, 0, stream>>>(ln2b, colsb);
    gemm_kernel<2, 1, float, u16><<<dim3(8, 98), 256, 0, stream>>>(
        colsb, wt_fc1, fc1_b, (const float*)nullptr, hb, 12544, 1024, 1600);
    gemm_kernel<3, 2, float, float><<<dim3(5, 98), 256, 0, stream>>>(
        hb, wt_fc2, fc2_b, x1 + r0 * 576, x1 + r0 * 576, 12544, 576, 1024);
  }
}

// Round 8
// 577.975 us; speedup vs baseline: 1.2551x; 1.2551x over previous
//
#include <hip/hip_runtime.h>

typedef unsigned short u16;
typedef __bf16 bf16x8 __attribute__((ext_vector_type(8)));
typedef float f32x4 __attribute__((ext_vector_type(4)));

__device__ __forceinline__ float bf2f(u16 u) {
  union { unsigned int i; float f; } v; v.i = ((unsigned int)u) << 16; return v.f;
}
__device__ __forceinline__ u16 f2bf(float f) {
  union { float f; unsigned int i; } v; v.f = f;
  unsigned int i = v.i;
  return (u16)((i + 0x7fffu + ((i >> 16) & 1u)) >> 16);  // RNE
}
__device__ __forceinline__ float ldf(const float* p) { return *p; }
__device__ __forceinline__ float ldf(const u16* p) { return bf2f(*p); }

// async global->LDS, 16B per lane. LDS dest must be the wave-uniform base
// (HW writes base + lane*16); the GLOBAL source IS per-lane (m173).
__device__ __forceinline__ void load_lds16(const u16* g, u16* l) {
  __builtin_amdgcn_global_load_lds(
      (const __attribute__((address_space(1))) unsigned int*)g,
      (__attribute__((address_space(3))) unsigned int*)l, 16, 0, 0);
}

// ---------------- weight transpose + cast: Wt[n*K+k] = bf16(W[k*N+n]) ----
__global__ void transpose_kernel(const float* __restrict__ W, u16* __restrict__ Wt,
                                 int K, int N) {
  int idx = blockIdx.x * 256 + threadIdx.x;
  if (idx >= K * N) return;
  int k = idx / N, n = idx % N;
  Wt[n * K + k] = f2bf(W[idx]);
}

// fc1 weights: transpose + K-reorder nf*25+p -> p*64+nf (matches ps layout)
__global__ void transpose_fc1_kernel(const float* __restrict__ W, u16* __restrict__ Wt) {
  int idx = blockIdx.x * 256 + threadIdx.x;
  if (idx >= 1600 * 1024) return;
  int k = idx >> 10, n = idx & 1023;      // k = nf*25+p (reference order)
  int nf = k / 25, p = k - nf * 25;
  Wt[n * 1600 + p * 64 + nf] = f2bf(W[idx]);
}

// ---------------- layernorm over C=576, 4 rows/block (1 wave each) -------
template <typename T>
__global__ __launch_bounds__(256) void ln_kernel(const T* __restrict__ x,
                                                 const float* __restrict__ w,
                                                 const float* __restrict__ b,
                                                 u16* __restrict__ out) {
  int wave = threadIdx.x >> 6, lane = threadIdx.x & 63;
  long row = (long)blockIdx.x * 4 + wave;
  const T* xr = x + row * 576;
  float v[9];
  float sum = 0.f;
  #pragma unroll
  for (int i = 0; i < 9; ++i) { v[i] = ldf(&xr[lane + i * 64]); sum += v[i]; }
  #pragma unroll
  for (int off = 32; off; off >>= 1) sum += __shfl_xor(sum, off);
  float mean = sum * (1.0f / 576.0f);
  float var = 0.f;
  #pragma unroll
  for (int i = 0; i < 9; ++i) { float d = v[i] - mean; var += d * d; }
  #pragma unroll
  for (int off = 32; off; off >>= 1) var += __shfl_xor(var, off);
  float rstd = rsqrtf(var * (1.0f / 576.0f) + 1e-5f);
  u16* outr = out + row * 576;
  #pragma unroll
  for (int i = 0; i < 9; ++i) {
    int c = lane + i * 64;
    outr[c] = f2bf((v[i] - mean) * rstd * w[c] + b[c]);
  }
}

// ---------------- phase-2 LN -> pixelshuffled layout ---------------------
// ps[b][R=3*h2+a][C=3*w2+b2][nf] = LN(x1)[b, h2*56+w2, nf*9+a*3+b2]
// LDS shuffle per wave-row, then 9 coalesced 128B chunk writes.
__global__ __launch_bounds__(256) void ln_ps_kernel(const float* __restrict__ x,
                                                    const float* __restrict__ w,
                                                    const float* __restrict__ b,
                                                    u16* __restrict__ ps) {
  __shared__ u16 sh[4][576];
  int wave = threadIdx.x >> 6, lane = threadIdx.x & 63;
  long row = (long)blockIdx.x * 4 + wave;
  const float* xr = x + row * 576;
  float v[9];
  float sum = 0.f;
  #pragma unroll
  for (int i = 0; i < 9; ++i) { v[i] = xr[lane + i * 64]; sum += v[i]; }
  #pragma unroll
  for (int off = 32; off; off >>= 1) sum += __shfl_xor(sum, off);
  float mean = sum * (1.0f / 576.0f);
  float var = 0.f;
  #pragma unroll
  for (int i = 0; i < 9; ++i) { float d = v[i] - mean; var += d * d; }
  #pragma unroll
  for (int off = 32; off; off >>= 1) var += __shfl_xor(var, off);
  float rstd = rsqrtf(var * (1.0f / 576.0f) + 1e-5f);
  #pragma unroll
  for (int i = 0; i < 9; ++i) {
    int c = lane + i * 64;
    sh[wave][c] = f2bf((v[i] - mean) * rstd * w[c] + b[c]);
  }
  __syncthreads();
  int bb = (int)(row / 3136), ij = (int)(row % 3136);
  int h2 = ij / 56, w2 = ij - h2 * 56;
  #pragma unroll
  for (int a = 0; a < 3; ++a)
    #pragma unroll
    for (int b2 = 0; b2 < 3; ++b2) {
      u16 val = sh[wave][lane * 9 + a * 3 + b2];       // nf = lane
      long off = (((long)bb * 168 + 3 * h2 + a) * 168 + (3 * w2 + b2)) * 64 + lane;
      ps[off] = val;
    }
}

// ---------------- window attention, MFMA version -------------------------
__constant__ int c_di[25] = {0,0,0, 1,1,1, 2,2,2, 3,3,3,3,3,3,3, 4,4,4, 5,5,5, 6,6,6};
__constant__ int c_dj[25] = {0,3,6, 1,3,5, 2,3,4, 0,1,2,3,4,5,6, 2,3,4, 1,3,5, 0,3,6};

__global__ __launch_bounds__(256) void attn_kernel(const u16* __restrict__ qkv,
                                                   const float* __restrict__ rpb,
                                                   u16* __restrict__ obuf) {
  int h = blockIdx.y;            // 0..5
  int wi = blockIdx.x;
  int b = wi >> 6, w = wi & 63, wr = w >> 3, wc = w & 7;
  __shared__ __align__(16) u16 Qs[64 * 104];
  __shared__ __align__(16) u16 Ks[64 * 104];
  __shared__ __align__(16) u16 Vt[96 * 72];
  __shared__ __align__(16) u16 Ps[64 * 72];
  int tid = threadIdx.x;
  int lane = tid & 63, wv = tid >> 6;
  int quad = lane >> 4, l15 = lane & 15;
  const float scale = 0.1020620726159658f;  // 96^-0.5

  long base = ((long)b * 3136 + wr * 7 * 56 + wc * 7) * 1728 + h * 96;

  for (int idx = tid; idx < 588; idx += 256) {
    int t = idx / 12, dq = idx % 12;
    int tr = t / 7, tc = t - tr * 7;
    long roff = base + (tr * 56 + tc) * 1728 + dq * 8;
    *(uint4*)&Qs[t * 104 + dq * 8] = *(const uint4*)(qkv + roff);
    *(uint4*)&Ks[t * 104 + dq * 8] = *(const uint4*)(qkv + roff + 576);
  }
  for (int idx = tid; idx < 96 * 15; idx += 256) {
    int d = idx / 15, t = 49 + idx % 15;
    Vt[d * 72 + t] = 0;
  }
  for (int idx = tid; idx < 768; idx += 256) {
    int dq = idx >> 6, t = idx & 63;
    if (t < 49) {
      int tr = t / 7, tc = t - tr * 7;
      uint4 v = *(const uint4*)(qkv + base + (tr * 56 + tc) * 1728 + 1152 + dq * 8);
      const u16* vv = (const u16*)&v;
      #pragma unroll
      for (int kk = 0; kk < 8; ++kk) Vt[(dq * 8 + kk) * 72 + t] = vv[kk];
    }
  }
  __syncthreads();

  f32x4 accS[4] = {};
  #pragma unroll
  for (int k0 = 0; k0 < 3; ++k0) {
    bf16x8 aq = *(const bf16x8*)&Qs[(wv * 16 + l15) * 104 + k0 * 32 + quad * 8];
    #pragma unroll
    for (int nt = 0; nt < 4; ++nt) {
      bf16x8 bk = *(const bf16x8*)&Ks[(nt * 16 + l15) * 104 + k0 * 32 + quad * 8];
      accS[nt] = __builtin_amdgcn_mfma_f32_16x16x32_bf16(aq, bk, accS[nt], 0, 0, 0);
    }
  }

  #pragma unroll
  for (int r = 0; r < 4; ++r) {
    int rg = wv * 16 + quad * 4 + r;
    int yi = rg / 7, xi = rg - yi * 7;
    float sv[4];
    float mx = -3e38f;
    #pragma unroll
    for (int nt = 0; nt < 4; ++nt) {
      int col = nt * 16 + l15;
      float s = accS[nt][r] * scale;
      if (rg < 49 && col < 49) {
        int yj = col / 7, xj = col - yj * 7;
        s += rpb[((yi - yj + 6) * 13 + (xi - xj + 6)) * 6 + h];
      } else {
        s = -3e38f;
      }
      sv[nt] = s;
      mx = fmaxf(mx, s);
    }
    #pragma unroll
    for (int off = 8; off; off >>= 1) mx = fmaxf(mx, __shfl_xor(mx, off));
    float sum = 0.f;
    #pragma unroll
    for (int nt = 0; nt < 4; ++nt) { sv[nt] = __expf(sv[nt] - mx); sum += sv[nt]; }
    #pragma unroll
    for (int off = 8; off; off >>= 1) sum += __shfl_xor(sum, off);
    float inv = 1.0f / sum;
    u16* psr = Ps + rg * 72;
    #pragma unroll
    for (int nt = 0; nt < 4; ++nt) psr[nt * 16 + l15] = f2bf(sv[nt] * inv);
  }
  __syncthreads();

  f32x4 accO[6] = {};
  #pragma unroll
  for (int k0 = 0; k0 < 2; ++k0) {
    bf16x8 ap = *(const bf16x8*)&Ps[(wv * 16 + l15) * 72 + k0 * 32 + quad * 8];
    #pragma unroll
    for (int nt = 0; nt < 6; ++nt) {
      bf16x8 bv = *(const bf16x8*)&Vt[(nt * 16 + l15) * 72 + k0 * 32 + quad * 8];
      accO[nt] = __builtin_amdgcn_mfma_f32_16x16x32_bf16(ap, bv, accO[nt], 0, 0, 0);
    }
  }
  #pragma unroll
  for (int r = 0; r < 4; ++r) {
    int rg = wv * 16 + quad * 4 + r;
    if (rg < 49) {
      int tr = rg / 7, tc = rg - tr * 7;
      long ooff = ((long)b * 3136 + (wr * 7 + tr) * 56 + wc * 7 + tc) * 576 + h * 96;
      #pragma unroll
      for (int nt = 0; nt < 6; ++nt) obuf[ooff + nt * 16 + l15] = f2bf(accO[nt][r]);
    }
  }
}

// ---------------- generic bf16 MFMA GEMM (qkv / proj / fc2) --------------
// 128x128x32 tile, 4 waves, global_load_lds, triple-buffer depth-2
// (R5-verified best for these L2-resident-A GEMMs), XCD-chunked swizzle.
template <int EPI, typename TR, typename TO>
__global__ __launch_bounds__(256) void gemm_kernel(const u16* __restrict__ A,
                                                   const u16* __restrict__ Bt,
                                                   const float* __restrict__ bias,
                                                   const TR* __restrict__ res,
                                                   TO* __restrict__ C,
                                                   int M, int N, int K) {
  __shared__ __align__(16) u16 As[3][128 * 32];
  __shared__ __align__(16) u16 Bs[3][128 * 32];

  int nwg = gridDim.x * gridDim.y;
  int flat = blockIdx.y * gridDim.x + blockIdx.x;
  int q = nwg >> 3, r = nwg & 7;
  int xcd = flat & 7, loc = flat >> 3;
  int newflat = ((xcd < r) ? xcd * (q + 1) : r * (q + 1) + (xcd - r) * q) + loc;
  int nblk = newflat % gridDim.x, mblk = newflat / gridDim.x;
  int n0 = nblk * 128;
  int m0 = mblk * 128;

  int tid = threadIdx.x;
  int lane = tid & 63, wv = tid >> 6;
  int quad = lane >> 4, l15 = lane & 15;
  int wr2 = wv >> 1, wc2 = wv & 1;
  f32x4 acc[4][4] = {};

  int rA0 = tid >> 2, rA1 = 64 + (tid >> 2);
  int kc0 = (tid & 3) * 8;
  int rB0 = n0 + rA0; if (rB0 > N - 1) rB0 = N - 1;
  int rB1 = n0 + rA1; if (rB1 > N - 1) rB1 = N - 1;
  const u16* gA0 = A + (long)(m0 + rA0) * K + kc0;
  const u16* gA1 = A + (long)(m0 + rA1) * K + kc0;
  const u16* gB0 = Bt + (long)rB0 * K + kc0;
  const u16* gB1 = Bt + (long)rB1 * K + kc0;
  int lo0 = (wv * 64) * 8, lo1 = (256 + wv * 64) * 8;

  int nt = K >> 5;
  auto stage = [&](int bufi, int kk) {
    load_lds16(gA0 + kk, &As[bufi][lo0]);
    load_lds16(gA1 + kk, &As[bufi][lo1]);
    load_lds16(gB0 + kk, &Bs[bufi][lo0]);
    load_lds16(gB1 + kk, &Bs[bufi][lo1]);
  };
  auto compute = [&](int cur) {
    bf16x8 a[4], bfr[4];
    const u16* as = &As[cur][(wr2 * 64 + l15) * 32 + quad * 8];
    const u16* bs = &Bs[cur][(wc2 * 64 + l15) * 32 + quad * 8];
    #pragma unroll
    for (int mi = 0; mi < 4; ++mi) a[mi] = *(const bf16x8*)(as + mi * 512);
    #pragma unroll
    for (int ni = 0; ni < 4; ++ni) bfr[ni] = *(const bf16x8*)(bs + ni * 512);
    #pragma unroll
    for (int mi = 0; mi < 4; ++mi)
      #pragma unroll
      for (int ni = 0; ni < 4; ++ni)
        acc[mi][ni] = __builtin_amdgcn_mfma_f32_16x16x32_bf16(a[mi], bfr[ni], acc[mi][ni], 0, 0, 0);
  };

  stage(0, 0);
  stage(1, 32);
  int cur = 0, nx2 = 2;
  for (int t = 0; t < nt; ++t) {
    if (t + 2 < nt) {
      stage(nx2, (t + 2) * 32);
      asm volatile("s_waitcnt vmcnt(8)" ::: "memory");
    } else if (t + 1 < nt) {
      asm volatile("s_waitcnt vmcnt(4)" ::: "memory");
    } else {
      asm volatile("s_waitcnt vmcnt(0)" ::: "memory");
    }
    __builtin_amdgcn_s_barrier();
    compute(cur);
    __builtin_amdgcn_s_barrier();
    cur = cur + 1; if (cur == 3) cur = 0;
    nx2 = nx2 + 1; if (nx2 == 3) nx2 = 0;
  }

  #pragma unroll
  for (int mi = 0; mi < 4; ++mi)
    #pragma unroll
    for (int ni = 0; ni < 4; ++ni) {
      int col = n0 + wc2 * 64 + ni * 16 + l15;
      if (col < N) {
        float bz = bias[col];
        #pragma unroll
        for (int rr = 0; rr < 4; ++rr) {
          int row = m0 + wr2 * 64 + mi * 16 + quad * 4 + rr;
          float v = acc[mi][ni][rr] + bz;
          if (EPI == 1) v = 0.5f * v * (1.0f + erff(v * 0.70710678118654752f));
          if (EPI == 2) v += ldf(&res[(long)row * N + col]);
          long off = (long)row * N + col;
          if (sizeof(TO) == 2) ((u16*)C)[off] = f2bf(v);
          else                 ((float*)C)[off] = v;
        }
      }
    }
}

// ---------------- fc1: fused gather + GEMM + GELU ------------------------
// C(25088,1024) = cols(25088,1600) @ Wt^T, where cols[n][p*64+nf] is read
// DIRECTLY from ps[b][R][C][nf] via per-lane computed global_load_lds
// addresses (no colsb materialization, no gather kernel).
// K order p-major: per K-step t (BK=32), p = t>>1 is thread-UNIFORM;
// nf0 = ((t&1)<<5) + (tid&3)*8. di/dj tables live in LDS so the address
// path stays in the lgkmcnt domain (vmcnt counting untouched).
// Depth-1 double-buffer (R4/R7-verified best for fc1). N=1024: no col guard.
__global__ __launch_bounds__(256) void fc1_kernel(const u16* __restrict__ ps,
                                                  const u16* __restrict__ Bt,
                                                  const float* __restrict__ bias,
                                                  u16* __restrict__ C) {
  const int N = 1024, K = 1600;
  __shared__ __align__(16) u16 As[2][128 * 32];
  __shared__ __align__(16) u16 Bs[2][128 * 32];
  __shared__ int s_di[25], s_dj[25];
  if (threadIdx.x < 25) {
    s_di[threadIdx.x] = c_di[threadIdx.x];
    s_dj[threadIdx.x] = c_dj[threadIdx.x];
  }

  int nwg = gridDim.x * gridDim.y;          // 1568, %8 == 0
  int flat = blockIdx.y * gridDim.x + blockIdx.x;
  int q = nwg >> 3;
  int xcd = flat & 7, loc = flat >> 3;
  int newflat = xcd * q + loc;
  int nblk = newflat % gridDim.x, mblk = newflat / gridDim.x;
  int n0 = nblk * 128;
  int m0 = mblk * 128;

  int tid = threadIdx.x;
  int lane = tid & 63, wv = tid >> 6;
  int quad = lane >> 4, l15 = lane & 15;
  int wr2 = wv >> 1, wc2 = wv & 1;
  f32x4 acc[4][4] = {};

  int rA0 = tid >> 2, rA1 = 64 + (tid >> 2);
  int kc0 = (tid & 3) * 8;
  // decompose A rows -> (b, i, j)
  int m0_ = m0 + rA0;
  int b0 = m0_ / 3136, ij0 = m0_ % 3136, i0 = ij0 / 56, j0 = ij0 - i0 * 56;
  int m1_ = m0 + rA1;
  int b1 = m1_ / 3136, ij1 = m1_ % 3136, i1 = ij1 / 56, j1 = ij1 - i1 * 56;
  const u16* gB0 = Bt + (long)(n0 + rA0) * K + kc0;
  const u16* gB1 = Bt + (long)(n0 + rA1) * K + kc0;
  int lo0 = (wv * 64) * 8, lo1 = (256 + wv * 64) * 8;

  __syncthreads();                           // s_di/s_dj ready

  auto stage = [&](int bufi, int t) {
    int p = t >> 1;                          // uniform
    int dip = s_di[p], djp = s_dj[p];        // LDS broadcast (lgkmcnt)
    int nf0 = ((t & 1) << 5) + kc0;
    int R0 = 3 * i0 - 2 + dip; R0 = R0 < 0 ? -R0 : R0; R0 = R0 >= 168 ? 334 - R0 : R0;
    int C0 = 3 * j0 - 2 + djp; C0 = C0 < 0 ? -C0 : C0; C0 = C0 >= 168 ? 334 - C0 : C0;
    int R1 = 3 * i1 - 2 + dip; R1 = R1 < 0 ? -R1 : R1; R1 = R1 >= 168 ? 334 - R1 : R1;
    int C1 = 3 * j1 - 2 + djp; C1 = C1 < 0 ? -C1 : C1; C1 = C1 >= 168 ? 334 - C1 : C1;
    const u16* a0 = ps + (((long)b0 * 168 + R0) * 168 + C0) * 64 + nf0;
    const u16* a1 = ps + (((long)b1 * 168 + R1) * 168 + C1) * 64 + nf0;
    load_lds16(a0, &As[bufi][lo0]);
    load_lds16(a1, &As[bufi][lo1]);
    load_lds16(gB0 + t * 32, &Bs[bufi][lo0]);
    load_lds16(gB1 + t * 32, &Bs[bufi][lo1]);
  };
  auto compute = [&](int cur) {
    bf16x8 a[4], bfr[4];
    const u16* as = &As[cur][(wr2 * 64 + l15) * 32 + quad * 8];
    const u16* bs = &Bs[cur][(wc2 * 64 + l15) * 32 + quad * 8];
    #pragma unroll
    for (int mi = 0; mi < 4; ++mi) a[mi] = *(const bf16x8*)(as + mi * 512);
    #pragma unroll
    for (int ni = 0; ni < 4; ++ni) bfr[ni] = *(const bf16x8*)(bs + ni * 512);
    #pragma unroll
    for (int mi = 0; mi < 4; ++mi)
      #pragma unroll
      for (int ni = 0; ni < 4; ++ni)
        acc[mi][ni] = __builtin_amdgcn_mfma_f32_16x16x32_bf16(a[mi], bfr[ni], acc[mi][ni], 0, 0, 0);
  };

  const int nt = K >> 5;                     // 50
  stage(0, 0);
  for (int t = 0; t < nt - 1; ++t) {
    int cur = t & 1;
    stage(cur ^ 1, t + 1);
    asm volatile("s_waitcnt vmcnt(4)" ::: "memory");
    __builtin_amdgcn_s_barrier();
    compute(cur);
    __builtin_amdgcn_s_barrier();
  }
  asm volatile("s_waitcnt vmcnt(0)" ::: "memory");
  __builtin_amdgcn_s_barrier();
  compute((nt - 1) & 1);

  #pragma unroll
  for (int mi = 0; mi < 4; ++mi)
    #pragma unroll
    for (int ni = 0; ni < 4; ++ni) {
      int col = n0 + wc2 * 64 + ni * 16 + l15;
      float bz = bias[col];
      #pragma unroll
      for (int rr = 0; rr < 4; ++rr) {
        int row = m0 + wr2 * 64 + mi * 16 + quad * 4 + rr;
        float v = acc[mi][ni][rr] + bz;
        v = 0.5f * v * (1.0f + erff(v * 0.70710678118654752f));   // exact GELU
        C[(long)row * N + col] = f2bf(v);
      }
    }
}

// ---------------- host launch -------------------------------------------
// Inputs fp32, OUTPUT FP32. ws peak ~87.4 MB.
// x1 lives in d_out f32 (proj writes, ln_ps reads, fc2 res+overwrite in
// place -- idempotent under graph replay). Phase 2 is one full-batch pass:
// ln_ps -> fc1 (fused gather) -> fc2.
extern "C" void kernel_launch(void* const* d_in, const int* in_sizes, int n_in,
                              void* d_out, int out_size, void* d_ws, size_t ws_size,
                              hipStream_t stream) {
  const float* x      = (const float*)d_in[0];
  const float* n1w    = (const float*)d_in[1];
  const float* n1b    = (const float*)d_in[2];
  const float* qkv_w  = (const float*)d_in[3];
  const float* qkv_b  = (const float*)d_in[4];
  const float* rpb    = (const float*)d_in[5];
  const float* proj_w = (const float*)d_in[6];
  const float* proj_b = (const float*)d_in[7];
  const float* n2w    = (const float*)d_in[8];
  const float* n2b    = (const float*)d_in[9];
  const float* fc1_w  = (const float*)d_in[10];
  const float* fc1_b  = (const float*)d_in[11];
  const float* fc2_w  = (const float*)d_in[12];
  const float* fc2_b  = (const float*)d_in[13];

  char* ws = (char*)d_ws;
  u16* wt_qkv  = (u16*)(ws + 0);           // 1728x576
  u16* wt_proj = (u16*)(ws + 1990656);     // 576x576
  u16* wt_fc1  = (u16*)(ws + 2654208);     // 1024x1600 (K = p*64+nf order)
  u16* wt_fc2  = (u16*)(ws + 5931008);     // 576x1024
  // phase 1 pools (freed before phase 2):
  char* qkvpool = ws + 7110656;            // 43,352,064 B (qkvb, half)
  char* lnpool  = ws + 50462720;           // 14,450,688 B (lnb, half)
  // phase 2 pools (overlay phase-1 region; stream-ordered):
  u16* ln2ps = (u16*)(ws + 7110656);       // 8x168x168x64 bf16 = 28,901,376 B
  u16* hb    = (u16*)(ws + 36012032);      // 25088x1024 bf16 = 51,380,224 B -> 87,392,256
  float* x1 = (float*)d_out;               // 25088x576 f32

  transpose_kernel<<<3888, 256, 0, stream>>>(qkv_w, wt_qkv, 576, 1728);
  transpose_kernel<<<1296, 256, 0, stream>>>(proj_w, wt_proj, 576, 576);
  transpose_fc1_kernel<<<6400, 256, 0, stream>>>(fc1_w, wt_fc1);
  transpose_kernel<<<2304, 256, 0, stream>>>(fc2_w, wt_fc2, 1024, 576);

  // ---------- phase 1: two halves of 4 batches (12544 rows each) ----------
  for (int h = 0; h < 2; ++h) {
    const long r0 = (long)h * 12544;
    u16* lnb  = (u16*)lnpool;
    u16* qkvb = (u16*)qkvpool;
    ln_kernel<float><<<3136, 256, 0, stream>>>(x + r0 * 576, n1w, n1b, lnb);
    gemm_kernel<0, float, u16><<<dim3(14, 98), 256, 0, stream>>>(
        lnb, wt_qkv, qkv_b, (const float*)nullptr, qkvb, 12544, 1728, 576);
    attn_kernel<<<dim3(256, 6), 256, 0, stream>>>(qkvb, rpb, lnb);
    gemm_kernel<2, float, float><<<dim3(5, 98), 256, 0, stream>>>(
        lnb, wt_proj, proj_b, x + r0 * 576, x1 + r0 * 576, 12544, 576, 576);
  }

  // ---------- phase 2: full batch, one pass ----------
  ln_ps_kernel<<<6272, 256, 0, stream>>>(x1, n2w, n2b, ln2ps);
  fc1_kernel<<<dim3(8, 196), 256, 0, stream>>>(ln2ps, wt_fc1, fc1_b, hb);
  gemm_kernel<2, float, float><<<dim3(5, 196), 256, 0, stream>>>(
      hb, wt_fc2, fc2_b, x1, x1, 25088, 576, 1024);
}

// Round 9
// 534.547 us; speedup vs baseline: 1.3571x; 1.0812x over previous
//
#include <hip/hip_runtime.h>

typedef unsigned short u16;
typedef __bf16 bf16x8 __attribute__((ext_vector_type(8)));
typedef float f32x4 __attribute__((ext_vector_type(4)));

__device__ __forceinline__ float bf2f(u16 u) {
  union { unsigned int i; float f; } v; v.i = ((unsigned int)u) << 16; return v.f;
}
__device__ __forceinline__ u16 f2bf(float f) {
  union { float f; unsigned int i; } v; v.f = f;
  unsigned int i = v.i;
  return (u16)((i + 0x7fffu + ((i >> 16) & 1u)) >> 16);  // RNE
}
__device__ __forceinline__ float ldf(const float* p) { return *p; }
__device__ __forceinline__ float ldf(const u16* p) { return bf2f(*p); }

// exact-GELU via Abramowitz-Stegun 7.1.26 erf (|err| <= 1.5e-7, branchless):
// ~14 VALU vs ocml erff's ~40 with divergent branches.
__device__ __forceinline__ float gelu_f(float v) {
  float x = fabsf(v) * 0.70710678118654752f;
  float t = __builtin_amdgcn_rcpf(fmaf(0.3275911f, x, 1.0f));
  float poly = t * fmaf(t, fmaf(t, fmaf(t, fmaf(t, 1.061405429f, -1.453152027f),
                                        1.421413741f), -0.284496736f), 0.254829592f);
  float er = fmaf(-poly, __expf(-x * x), 1.0f);      // erf(|x|)
  er = copysignf(er, v);
  return 0.5f * v * (1.0f + er);
}

// async global->LDS, 16B per lane. LDS dest must be the wave-uniform base
// (HW writes base + lane*16); the GLOBAL source IS per-lane (m173).
__device__ __forceinline__ void load_lds16(const u16* g, u16* l) {
  __builtin_amdgcn_global_load_lds(
      (const __attribute__((address_space(1))) unsigned int*)g,
      (__attribute__((address_space(3))) unsigned int*)l, 16, 0, 0);
}

// ---------------- weight transpose + cast: Wt[n*K+k] = bf16(W[k*N+n]) ----
__global__ void transpose_kernel(const float* __restrict__ W, u16* __restrict__ Wt,
                                 int K, int N) {
  int idx = blockIdx.x * 256 + threadIdx.x;
  if (idx >= K * N) return;
  int k = idx / N, n = idx % N;
  Wt[n * K + k] = f2bf(W[idx]);
}

// fc1 weights: transpose + K-reorder nf*25+p -> p*64+nf (matches ps layout)
__global__ void transpose_fc1_kernel(const float* __restrict__ W, u16* __restrict__ Wt) {
  int idx = blockIdx.x * 256 + threadIdx.x;
  if (idx >= 1600 * 1024) return;
  int k = idx >> 10, n = idx & 1023;      // k = nf*25+p (reference order)
  int nf = k / 25, p = k - nf * 25;
  Wt[n * 1600 + p * 64 + nf] = f2bf(W[idx]);
}

// ---------------- layernorm over C=576, 4 rows/block (1 wave each) -------
template <typename T>
__global__ __launch_bounds__(256) void ln_kernel(const T* __restrict__ x,
                                                 const float* __restrict__ w,
                                                 const float* __restrict__ b,
                                                 u16* __restrict__ out) {
  int wave = threadIdx.x >> 6, lane = threadIdx.x & 63;
  long row = (long)blockIdx.x * 4 + wave;
  const T* xr = x + row * 576;
  float v[9];
  float sum = 0.f;
  #pragma unroll
  for (int i = 0; i < 9; ++i) { v[i] = ldf(&xr[lane + i * 64]); sum += v[i]; }
  #pragma unroll
  for (int off = 32; off; off >>= 1) sum += __shfl_xor(sum, off);
  float mean = sum * (1.0f / 576.0f);
  float var = 0.f;
  #pragma unroll
  for (int i = 0; i < 9; ++i) { float d = v[i] - mean; var += d * d; }
  #pragma unroll
  for (int off = 32; off; off >>= 1) var += __shfl_xor(var, off);
  float rstd = rsqrtf(var * (1.0f / 576.0f) + 1e-5f);
  u16* outr = out + row * 576;
  #pragma unroll
  for (int i = 0; i < 9; ++i) {
    int c = lane + i * 64;
    outr[c] = f2bf((v[i] - mean) * rstd * w[c] + b[c]);
  }
}

// ---------------- phase-2 LN -> pixelshuffled layout ---------------------
// ps[b][R=3*h2+a][C=3*w2+b2][nf] = LN(x1)[b, h2*56+w2, nf*9+a*3+b2]
__global__ __launch_bounds__(256) void ln_ps_kernel(const float* __restrict__ x,
                                                    const float* __restrict__ w,
                                                    const float* __restrict__ b,
                                                    u16* __restrict__ ps) {
  __shared__ u16 sh[4][576];
  int wave = threadIdx.x >> 6, lane = threadIdx.x & 63;
  long row = (long)blockIdx.x * 4 + wave;
  const float* xr = x + row * 576;
  float v[9];
  float sum = 0.f;
  #pragma unroll
  for (int i = 0; i < 9; ++i) { v[i] = xr[lane + i * 64]; sum += v[i]; }
  #pragma unroll
  for (int off = 32; off; off >>= 1) sum += __shfl_xor(sum, off);
  float mean = sum * (1.0f / 576.0f);
  float var = 0.f;
  #pragma unroll
  for (int i = 0; i < 9; ++i) { float d = v[i] - mean; var += d * d; }
  #pragma unroll
  for (int off = 32; off; off >>= 1) var += __shfl_xor(var, off);
  float rstd = rsqrtf(var * (1.0f / 576.0f) + 1e-5f);
  #pragma unroll
  for (int i = 0; i < 9; ++i) {
    int c = lane + i * 64;
    sh[wave][c] = f2bf((v[i] - mean) * rstd * w[c] + b[c]);
  }
  __syncthreads();
  int bb = (int)(row / 3136), ij = (int)(row % 3136);
  int h2 = ij / 56, w2 = ij - h2 * 56;
  #pragma unroll
  for (int a = 0; a < 3; ++a)
    #pragma unroll
    for (int b2 = 0; b2 < 3; ++b2) {
      u16 val = sh[wave][lane * 9 + a * 3 + b2];       // nf = lane
      long off = (((long)bb * 168 + 3 * h2 + a) * 168 + (3 * w2 + b2)) * 64 + lane;
      ps[off] = val;
    }
}

// ---------------- window attention, MFMA version -------------------------
__constant__ int c_di[25] = {0,0,0, 1,1,1, 2,2,2, 3,3,3,3,3,3,3, 4,4,4, 5,5,5, 6,6,6};
__constant__ int c_dj[25] = {0,3,6, 1,3,5, 2,3,4, 0,1,2,3,4,5,6, 2,3,4, 1,3,5, 0,3,6};

__global__ __launch_bounds__(256) void attn_kernel(const u16* __restrict__ qkv,
                                                   const float* __restrict__ rpb,
                                                   u16* __restrict__ obuf) {
  int h = blockIdx.y;            // 0..5
  int wi = blockIdx.x;
  int b = wi >> 6, w = wi & 63, wr = w >> 3, wc = w & 7;
  __shared__ __align__(16) u16 Qs[64 * 104];
  __shared__ __align__(16) u16 Ks[64 * 104];
  __shared__ __align__(16) u16 Vt[96 * 72];
  __shared__ __align__(16) u16 Ps[64 * 72];
  int tid = threadIdx.x;
  int lane = tid & 63, wv = tid >> 6;
  int quad = lane >> 4, l15 = lane & 15;
  const float scale = 0.1020620726159658f;  // 96^-0.5

  long base = ((long)b * 3136 + wr * 7 * 56 + wc * 7) * 1728 + h * 96;

  for (int idx = tid; idx < 588; idx += 256) {
    int t = idx / 12, dq = idx % 12;
    int tr = t / 7, tc = t - tr * 7;
    long roff = base + (tr * 56 + tc) * 1728 + dq * 8;
    *(uint4*)&Qs[t * 104 + dq * 8] = *(const uint4*)(qkv + roff);
    *(uint4*)&Ks[t * 104 + dq * 8] = *(const uint4*)(qkv + roff + 576);
  }
  for (int idx = tid; idx < 96 * 15; idx += 256) {
    int d = idx / 15, t = 49 + idx % 15;
    Vt[d * 72 + t] = 0;
  }
  for (int idx = tid; idx < 768; idx += 256) {
    int dq = idx >> 6, t = idx & 63;
    if (t < 49) {
      int tr = t / 7, tc = t - tr * 7;
      uint4 v = *(const uint4*)(qkv + base + (tr * 56 + tc) * 1728 + 1152 + dq * 8);
      const u16* vv = (const u16*)&v;
      #pragma unroll
      for (int kk = 0; kk < 8; ++kk) Vt[(dq * 8 + kk) * 72 + t] = vv[kk];
    }
  }
  __syncthreads();

  f32x4 accS[4] = {};
  #pragma unroll
  for (int k0 = 0; k0 < 3; ++k0) {
    bf16x8 aq = *(const bf16x8*)&Qs[(wv * 16 + l15) * 104 + k0 * 32 + quad * 8];
    #pragma unroll
    for (int nt = 0; nt < 4; ++nt) {
      bf16x8 bk = *(const bf16x8*)&Ks[(nt * 16 + l15) * 104 + k0 * 32 + quad * 8];
      accS[nt] = __builtin_amdgcn_mfma_f32_16x16x32_bf16(aq, bk, accS[nt], 0, 0, 0);
    }
  }

  #pragma unroll
  for (int r = 0; r < 4; ++r) {
    int rg = wv * 16 + quad * 4 + r;
    int yi = rg / 7, xi = rg - yi * 7;
    float sv[4];
    float mx = -3e38f;
    #pragma unroll
    for (int nt = 0; nt < 4; ++nt) {
      int col = nt * 16 + l15;
      float s = accS[nt][r] * scale;
      if (rg < 49 && col < 49) {
        int yj = col / 7, xj = col - yj * 7;
        s += rpb[((yi - yj + 6) * 13 + (xi - xj + 6)) * 6 + h];
      } else {
        s = -3e38f;
      }
      sv[nt] = s;
      mx = fmaxf(mx, s);
    }
    #pragma unroll
    for (int off = 8; off; off >>= 1) mx = fmaxf(mx, __shfl_xor(mx, off));
    float sum = 0.f;
    #pragma unroll
    for (int nt = 0; nt < 4; ++nt) { sv[nt] = __expf(sv[nt] - mx); sum += sv[nt]; }
    #pragma unroll
    for (int off = 8; off; off >>= 1) sum += __shfl_xor(sum, off);
    float inv = 1.0f / sum;
    u16* psr = Ps + rg * 72;
    #pragma unroll
    for (int nt = 0; nt < 4; ++nt) psr[nt * 16 + l15] = f2bf(sv[nt] * inv);
  }
  __syncthreads();

  f32x4 accO[6] = {};
  #pragma unroll
  for (int k0 = 0; k0 < 2; ++k0) {
    bf16x8 ap = *(const bf16x8*)&Ps[(wv * 16 + l15) * 72 + k0 * 32 + quad * 8];
    #pragma unroll
    for (int nt = 0; nt < 6; ++nt) {
      bf16x8 bv = *(const bf16x8*)&Vt[(nt * 16 + l15) * 72 + k0 * 32 + quad * 8];
      accO[nt] = __builtin_amdgcn_mfma_f32_16x16x32_bf16(ap, bv, accO[nt], 0, 0, 0);
    }
  }
  #pragma unroll
  for (int r = 0; r < 4; ++r) {
    int rg = wv * 16 + quad * 4 + r;
    if (rg < 49) {
      int tr = rg / 7, tc = rg - tr * 7;
      long ooff = ((long)b * 3136 + (wr * 7 + tr) * 56 + wc * 7 + tc) * 576 + h * 96;
      #pragma unroll
      for (int nt = 0; nt < 6; ++nt) obuf[ooff + nt * 16 + l15] = f2bf(accO[nt][r]);
    }
  }
}

// ---------------- generic bf16 MFMA GEMM (qkv / proj / fc2) --------------
// 128x128x32 tile, 4 waves, global_load_lds, triple-buffer depth-2
// (R5-verified best for these L2-resident-A GEMMs), XCD-chunked swizzle.
template <int EPI, typename TR, typename TO>
__global__ __launch_bounds__(256) void gemm_kernel(const u16* __restrict__ A,
                                                   const u16* __restrict__ Bt,
                                                   const float* __restrict__ bias,
                                                   const TR* __restrict__ res,
                                                   TO* __restrict__ C,
                                                   int M, int N, int K) {
  __shared__ __align__(16) u16 As[3][128 * 32];
  __shared__ __align__(16) u16 Bs[3][128 * 32];

  int nwg = gridDim.x * gridDim.y;
  int flat = blockIdx.y * gridDim.x + blockIdx.x;
  int q = nwg >> 3, r = nwg & 7;
  int xcd = flat & 7, loc = flat >> 3;
  int newflat = ((xcd < r) ? xcd * (q + 1) : r * (q + 1) + (xcd - r) * q) + loc;
  int nblk = newflat % gridDim.x, mblk = newflat / gridDim.x;
  int n0 = nblk * 128;
  int m0 = mblk * 128;

  int tid = threadIdx.x;
  int lane = tid & 63, wv = tid >> 6;
  int quad = lane >> 4, l15 = lane & 15;
  int wr2 = wv >> 1, wc2 = wv & 1;
  f32x4 acc[4][4] = {};

  int rA0 = tid >> 2, rA1 = 64 + (tid >> 2);
  int kc0 = (tid & 3) * 8;
  int rB0 = n0 + rA0; if (rB0 > N - 1) rB0 = N - 1;
  int rB1 = n0 + rA1; if (rB1 > N - 1) rB1 = N - 1;
  const u16* gA0 = A + (long)(m0 + rA0) * K + kc0;
  const u16* gA1 = A + (long)(m0 + rA1) * K + kc0;
  const u16* gB0 = Bt + (long)rB0 * K + kc0;
  const u16* gB1 = Bt + (long)rB1 * K + kc0;
  int lo0 = (wv * 64) * 8, lo1 = (256 + wv * 64) * 8;

  int nt = K >> 5;
  auto stage = [&](int bufi, int kk) {
    load_lds16(gA0 + kk, &As[bufi][lo0]);
    load_lds16(gA1 + kk, &As[bufi][lo1]);
    load_lds16(gB0 + kk, &Bs[bufi][lo0]);
    load_lds16(gB1 + kk, &Bs[bufi][lo1]);
  };
  auto compute = [&](int cur) {
    bf16x8 a[4], bfr[4];
    const u16* as = &As[cur][(wr2 * 64 + l15) * 32 + quad * 8];
    const u16* bs = &Bs[cur][(wc2 * 64 + l15) * 32 + quad * 8];
    #pragma unroll
    for (int mi = 0; mi < 4; ++mi) a[mi] = *(const bf16x8*)(as + mi * 512);
    #pragma unroll
    for (int ni = 0; ni < 4; ++ni) bfr[ni] = *(const bf16x8*)(bs + ni * 512);
    #pragma unroll
    for (int mi = 0; mi < 4; ++mi)
      #pragma unroll
      for (int ni = 0; ni < 4; ++ni)
        acc[mi][ni] = __builtin_amdgcn_mfma_f32_16x16x32_bf16(a[mi], bfr[ni], acc[mi][ni], 0, 0, 0);
  };

  stage(0, 0);
  stage(1, 32);
  int cur = 0, nx2 = 2;
  for (int t = 0; t < nt; ++t) {
    if (t + 2 < nt) {
      stage(nx2, (t + 2) * 32);
      asm volatile("s_waitcnt vmcnt(8)" ::: "memory");
    } else if (t + 1 < nt) {
      asm volatile("s_waitcnt vmcnt(4)" ::: "memory");
    } else {
      asm volatile("s_waitcnt vmcnt(0)" ::: "memory");
    }
    __builtin_amdgcn_s_barrier();
    compute(cur);
    __builtin_amdgcn_s_barrier();
    cur = cur + 1; if (cur == 3) cur = 0;
    nx2 = nx2 + 1; if (nx2 == 3) nx2 = 0;
  }

  #pragma unroll
  for (int mi = 0; mi < 4; ++mi)
    #pragma unroll
    for (int ni = 0; ni < 4; ++ni) {
      int col = n0 + wc2 * 64 + ni * 16 + l15;
      if (col < N) {
        float bz = bias[col];
        #pragma unroll
        for (int rr = 0; rr < 4; ++rr) {
          int row = m0 + wr2 * 64 + mi * 16 + quad * 4 + rr;
          float v = acc[mi][ni][rr] + bz;
          if (EPI == 1) v = gelu_f(v);
          if (EPI == 2) v += ldf(&res[(long)row * N + col]);
          long off = (long)row * N + col;
          if (sizeof(TO) == 2) ((u16*)C)[off] = f2bf(v);
          else                 ((float*)C)[off] = v;
        }
      }
    }
}

// ---------------- fc1: fused gather + GEMM + GELU ------------------------
// A-source addresses computed per-lane into global_load_lds from the
// pixelshuffled ps tensor (no colsb). VALU-slimmed (R9): loop-invariant
// u/v and per-batch base pointers hoisted; 32-bit element offsets
// (R*168+C)<<6 (all <2^24); unroll-2 so stage pairs sharing p CSE their
// reflect math; branchless A&S GELU epilogue.
__global__ __launch_bounds__(256) void fc1_kernel(const u16* __restrict__ ps,
                                                  const u16* __restrict__ Bt,
                                                  const float* __restrict__ bias,
                                                  u16* __restrict__ C) {
  const int N = 1024, K = 1600;
  __shared__ __align__(16) u16 As[2][128 * 32];
  __shared__ __align__(16) u16 Bs[2][128 * 32];
  __shared__ int s_di[25], s_dj[25];
  if (threadIdx.x < 25) {
    s_di[threadIdx.x] = c_di[threadIdx.x];
    s_dj[threadIdx.x] = c_dj[threadIdx.x];
  }

  int nwg = gridDim.x * gridDim.y;          // 1568, %8 == 0
  int flat = blockIdx.y * gridDim.x + blockIdx.x;
  int q = nwg >> 3;
  int xcd = flat & 7, loc = flat >> 3;
  int newflat = xcd * q + loc;
  int nblk = newflat % gridDim.x, mblk = newflat / gridDim.x;
  int n0 = nblk * 128;
  int m0 = mblk * 128;

  int tid = threadIdx.x;
  int lane = tid & 63, wv = tid >> 6;
  int quad = lane >> 4, l15 = lane & 15;
  int wr2 = wv >> 1, wc2 = wv & 1;
  f32x4 acc[4][4] = {};

  int rA0 = tid >> 2, rA1 = 64 + (tid >> 2);
  int kc0 = (tid & 3) * 8;
  // loop-invariant per-row terms
  int m0_ = m0 + rA0;
  int b0 = m0_ / 3136, ij0 = m0_ % 3136, i0 = ij0 / 56, j0 = ij0 - i0 * 56;
  int m1_ = m0 + rA1;
  int b1 = m1_ / 3136, ij1 = m1_ % 3136, i1 = ij1 / 56, j1 = ij1 - i1 * 56;
  int u0 = 3 * i0 - 2, v0 = 3 * j0 - 2;
  int u1 = 3 * i1 - 2, v1 = 3 * j1 - 2;
  const u16* psb0 = ps + (long)b0 * 1806336 + kc0;   // 168*168*64
  const u16* psb1 = ps + (long)b1 * 1806336 + kc0;
  const u16* gB0 = Bt + (long)(n0 + rA0) * K + kc0;
  const u16* gB1 = Bt + (long)(n0 + rA1) * K + kc0;
  int lo0 = (wv * 64) * 8, lo1 = (256 + wv * 64) * 8;

  __syncthreads();                           // s_di/s_dj ready

  auto stage = [&](int bufi, int t) {
    int p = t >> 1;                          // uniform
    int dip = s_di[p], djp = s_dj[p];
    int nf = (t & 1) << 5;
    int R0 = u0 + dip; R0 = R0 < 0 ? -R0 : R0; R0 = R0 >= 168 ? 334 - R0 : R0;
    int C0 = v0 + djp; C0 = C0 < 0 ? -C0 : C0; C0 = C0 >= 168 ? 334 - C0 : C0;
    int R1 = u1 + dip; R1 = R1 < 0 ? -R1 : R1; R1 = R1 >= 168 ? 334 - R1 : R1;
    int C1 = v1 + djp; C1 = C1 < 0 ? -C1 : C1; C1 = C1 >= 168 ? 334 - C1 : C1;
    load_lds16(psb0 + (((R0 * 168 + C0) << 6) + nf), &As[bufi][lo0]);
    load_lds16(psb1 + (((R1 * 168 + C1) << 6) + nf), &As[bufi][lo1]);
    load_lds16(gB0 + t * 32, &Bs[bufi][lo0]);
    load_lds16(gB1 + t * 32, &Bs[bufi][lo1]);
  };
  auto compute = [&](int cur) {
    bf16x8 a[4], bfr[4];
    const u16* as = &As[cur][(wr2 * 64 + l15) * 32 + quad * 8];
    const u16* bs = &Bs[cur][(wc2 * 64 + l15) * 32 + quad * 8];
    #pragma unroll
    for (int mi = 0; mi < 4; ++mi) a[mi] = *(const bf16x8*)(as + mi * 512);
    #pragma unroll
    for (int ni = 0; ni < 4; ++ni) bfr[ni] = *(const bf16x8*)(bs + ni * 512);
    #pragma unroll
    for (int mi = 0; mi < 4; ++mi)
      #pragma unroll
      for (int ni = 0; ni < 4; ++ni)
        acc[mi][ni] = __builtin_amdgcn_mfma_f32_16x16x32_bf16(a[mi], bfr[ni], acc[mi][ni], 0, 0, 0);
  };

  const int nt = K >> 5;                     // 50
  stage(0, 0);
  #pragma unroll 2
  for (int t = 0; t < nt - 1; ++t) {
    int cur = t & 1;
    stage(cur ^ 1, t + 1);
    asm volatile("s_waitcnt vmcnt(4)" ::: "memory");
    __builtin_amdgcn_s_barrier();
    compute(cur);
    __builtin_amdgcn_s_barrier();
  }
  asm volatile("s_waitcnt vmcnt(0)" ::: "memory");
  __builtin_amdgcn_s_barrier();
  compute((nt - 1) & 1);

  #pragma unroll
  for (int mi = 0; mi < 4; ++mi)
    #pragma unroll
    for (int ni = 0; ni < 4; ++ni) {
      int col = n0 + wc2 * 64 + ni * 16 + l15;
      float bz = bias[col];
      #pragma unroll
      for (int rr = 0; rr < 4; ++rr) {
        int row = m0 + wr2 * 64 + mi * 16 + quad * 4 + rr;
        C[(long)row * N + col] = f2bf(gelu_f(acc[mi][ni][rr] + bz));
      }
    }
}

// ---------------- host launch -------------------------------------------
// Inputs fp32, OUTPUT FP32. ws peak ~87.4 MB.
// x1 lives in d_out f32 (proj writes, ln_ps reads, fc2 res+overwrite in
// place -- idempotent under graph replay). Phase 2 is one full-batch pass:
// ln_ps -> fc1 (fused gather) -> fc2.
extern "C" void kernel_launch(void* const* d_in, const int* in_sizes, int n_in,
                              void* d_out, int out_size, void* d_ws, size_t ws_size,
                              hipStream_t stream) {
  const float* x      = (const float*)d_in[0];
  const float* n1w    = (const float*)d_in[1];
  const float* n1b    = (const float*)d_in[2];
  const float* qkv_w  = (const float*)d_in[3];
  const float* qkv_b  = (const float*)d_in[4];
  const float* rpb    = (const float*)d_in[5];
  const float* proj_w = (const float*)d_in[6];
  const float* proj_b = (const float*)d_in[7];
  const float* n2w    = (const float*)d_in[8];
  const float* n2b    = (const float*)d_in[9];
  const float* fc1_w  = (const float*)d_in[10];
  const float* fc1_b  = (const float*)d_in[11];
  const float* fc2_w  = (const float*)d_in[12];
  const float* fc2_b  = (const float*)d_in[13];

  char* ws = (char*)d_ws;
  u16* wt_qkv  = (u16*)(ws + 0);           // 1728x576
  u16* wt_proj = (u16*)(ws + 1990656);     // 576x576
  u16* wt_fc1  = (u16*)(ws + 2654208);     // 1024x1600 (K = p*64+nf order)
  u16* wt_fc2  = (u16*)(ws + 5931008);     // 576x1024
  // phase 1 pools (freed before phase 2):
  char* qkvpool = ws + 7110656;            // 43,352,064 B (qkvb, half)
  char* lnpool  = ws + 50462720;           // 14,450,688 B (lnb, half)
  // phase 2 pools (overlay phase-1 region; stream-ordered):
  u16* ln2ps = (u16*)(ws + 7110656);       // 8x168x168x64 bf16 = 28,901,376 B
  u16* hb    = (u16*)(ws + 36012032);      // 25088x1024 bf16 = 51,380,224 B -> 87,392,256
  float* x1 = (float*)d_out;               // 25088x576 f32

  transpose_kernel<<<3888, 256, 0, stream>>>(qkv_w, wt_qkv, 576, 1728);
  transpose_kernel<<<1296, 256, 0, stream>>>(proj_w, wt_proj, 576, 576);
  transpose_fc1_kernel<<<6400, 256, 0, stream>>>(fc1_w, wt_fc1);
  transpose_kernel<<<2304, 256, 0, stream>>>(fc2_w, wt_fc2, 1024, 576);

  // ---------- phase 1: two halves of 4 batches (12544 rows each) ----------
  for (int h = 0; h < 2; ++h) {
    const long r0 = (long)h * 12544;
    u16* lnb  = (u16*)lnpool;
    u16* qkvb = (u16*)qkvpool;
    ln_kernel<float><<<3136, 256, 0, stream>>>(x + r0 * 576, n1w, n1b, lnb);
    gemm_kernel<0, float, u16><<<dim3(14, 98), 256, 0, stream>>>(
        lnb, wt_qkv, qkv_b, (const float*)nullptr, qkvb, 12544, 1728, 576);
    attn_kernel<<<dim3(256, 6), 256, 0, stream>>>(qkvb, rpb, lnb);
    gemm_kernel<2, float, float><<<dim3(5, 98), 256, 0, stream>>>(
        lnb, wt_proj, proj_b, x + r0 * 576, x1 + r0 * 576, 12544, 576, 576);
  }

  // ---------- phase 2: full batch, one pass ----------
  ln_ps_kernel<<<6272, 256, 0, stream>>>(x1, n2w, n2b, ln2ps);
  fc1_kernel<<<dim3(8, 196), 256, 0, stream>>>(ln2ps, wt_fc1, fc1_b, hb);
  gemm_kernel<2, float, float><<<dim3(5, 196), 256, 0, stream>>>(
      hb, wt_fc2, fc2_b, x1, x1, 25088, 576, 1024);
}